// Round 5
// baseline (181.265 us; speedup 1.0000x reference)
//
#include <hip/hip_runtime.h>
#include <math.h>

#define IN_FEAT 4096
#define OUT_FEAT 2048
#define NUM_KNOTS 10
#define DEGREE 3
#define N_BASIS 6            // NUM_KNOTS - DEGREE - 1

#define TI 256               // threads per block
#define OPT 2                // outputs per thread
#define IBLK (TI * OPT)      // 512 outputs per block -> 4 i-groups
#define NIG (OUT_FEAT / IBLK)       // 4
#define JCHUNK 16            // input rows per chunk
#define NCHUNK (IN_FEAT / JCHUNK)   // 256 chunk-blocks per i-group

// Fused: per-chunk basis + partial dot + last-block-per-column reduce.
// Determinism: reduction is a fixed 0..NCHUNK-1 chain per output, performed
// by whichever block retires last (value independent of which one it is).
__global__ __launch_bounds__(TI) void kan_fused_kernel(
    const float* __restrict__ coeffs,    // [IN][OUT][N_BASIS]
    const float* __restrict__ bw,        // [IN][OUT]
    const float* __restrict__ x,         // [IN]
    float* __restrict__ partials,        // [NCHUNK][OUT]
    int* __restrict__ cnt,               // [NIG] retirement counters (zeroed per call)
    float* __restrict__ out) {           // [OUT]
    __shared__ float4 w4[JCHUNK][2];     // {B0..B3},{B4,B5,silu,pad} per j
    __shared__ int lastFlag;
    const int tid = threadIdx.x;
    const int ig = blockIdx.x;           // i-group 0..3
    const int j0 = blockIdx.y * JCHUNK;

    if (tid < JCHUNK) {
        float xv = x[j0 + tid];
        float t[NUM_KNOTS];
#pragma unroll
        for (int m = 0; m < NUM_KNOTS; ++m)
            t[m] = -1.0f + (2.0f / 9.0f) * (float)m;
        float N[NUM_KNOTS - 1];
#pragma unroll
        for (int m = 0; m < NUM_KNOTS - 1; ++m)
            N[m] = (xv >= t[m] && xv < t[m + 1]) ? 1.0f : 0.0f;
#pragma unroll
        for (int d = 1; d <= DEGREE; ++d) {
#pragma unroll
            for (int m = 0; m + d < NUM_KNOTS - 1; ++m) {
                float ld = t[m + d] - t[m];
                float rd = t[m + d + 1] - t[m + 1];
                float lv = (ld > 0.0f) ? (xv - t[m]) / ld * N[m] : 0.0f;
                float rv = (rd > 0.0f) ? (t[m + d + 1] - xv) / rd * N[m + 1] : 0.0f;
                N[m] = lv + rv;
            }
        }
        float* wp = (float*)&w4[tid][0];
#pragma unroll
        for (int k = 0; k < N_BASIS; ++k) wp[k] = N[k];
        wp[6] = xv / (1.0f + expf(-xv));   // silu
        wp[7] = 0.0f;
    }
    __syncthreads();

    const int i0 = ig * IBLK + tid * OPT;          // this thread's 2 outputs
    const float4* cp = (const float4*)(coeffs + ((size_t)j0 * OUT_FEAT + i0) * N_BASIS);
    const float2* bp = (const float2*)(bw + (size_t)j0 * OUT_FEAT + i0);

    float acc0 = 0.0f, acc1 = 0.0f;
#pragma unroll 4
    for (int j = 0; j < JCHUNK; ++j) {
        float4 a = cp[0];                 // i0:   c0 c1 c2 c3
        float4 b = cp[1];                 //       c4 c5 | i0+1: c0 c1
        float4 c = cp[2];                 //       c2 c3 c4 c5
        float2 bb = bp[0];
        float4 w0 = w4[j][0];             // B0..B3   (LDS broadcast)
        float4 w1 = w4[j][1];             // B4,B5,silu,pad
        acc0 += a.x * w0.x + a.y * w0.y + a.z * w0.z + a.w * w0.w
              + b.x * w1.x + b.y * w1.y + bb.x * w1.z;
        acc1 += b.z * w0.x + b.w * w0.y + c.x * w0.z + c.y * w0.w
              + c.z * w1.x + c.w * w1.y + bb.y * w1.z;
        cp += OUT_FEAT * N_BASIS / 4;
        bp += OUT_FEAT / 2;
    }
    ((float2*)(partials + (size_t)blockIdx.y * OUT_FEAT + i0))[0] = make_float2(acc0, acc1);

    // ---- retirement: last block of this i-group column reduces it ----
    __threadfence();                     // release: partials visible device-wide
    __syncthreads();                     // all threads' fences done before count
    if (tid == 0) {
        int v = atomicAdd(&cnt[ig], 1);  // device-scope
        lastFlag = (v == NCHUNK - 1);
    }
    __syncthreads();
    if (lastFlag) {
        __threadfence();                 // acquire: see all columns' partials
        const int col2 = ig * (IBLK / 2) + tid;        // float2 column index
        const float2* p2 = (const float2*)partials + col2;
        float sx = 0.0f, sy = 0.0f;
#pragma unroll 8
        for (int c = 0; c < NCHUNK; ++c) {
            float2 v2 = p2[(size_t)c * (OUT_FEAT / 2)];
            sx += v2.x; sy += v2.y;
        }
        ((float2*)out)[col2] = make_float2(sx, sy);
    }
}

extern "C" void kernel_launch(void* const* d_in, const int* in_sizes, int n_in,
                              void* d_out, int out_size, void* d_ws, size_t ws_size,
                              hipStream_t stream) {
    const float* x      = (const float*)d_in[0];   // [4096]
    const float* coeffs = (const float*)d_in[1];   // [4096][2048][6]
    const float* bw     = (const float*)d_in[2];   // [4096][2048]
    float* out = (float*)d_out;                    // [2048] fp32

    float* partials = (float*)d_ws;                          // NCHUNK*2048 floats (2 MB)
    int*   cnt      = (int*)(partials + (size_t)NCHUNK * OUT_FEAT);  // NIG ints

    hipMemsetAsync(cnt, 0, NIG * sizeof(int), stream);       // graph-safe memset node

    dim3 grid(NIG, NCHUNK);                        // (4, 256) = 1024 blocks
    kan_fused_kernel<<<grid, TI, 0, stream>>>(coeffs, bw, x, partials, cnt, out);
}

// Round 8
// 59.426 us; speedup vs baseline: 3.0503x; 3.0503x over previous
//
#include <hip/hip_runtime.h>
#include <math.h>

#define IN_FEAT 4096
#define OUT_FEAT 2048
#define NUM_KNOTS 10
#define DEGREE 3
#define N_BASIS 6            // NUM_KNOTS - DEGREE - 1

#define TI 256               // threads per block (main kernel)
#define OPT 2                // outputs per thread
#define IBLK (TI * OPT)      // 512 outputs per block
#define JCHUNK 16            // input rows per chunk
#define NCHUNK (IN_FEAT / JCHUNK)   // 256
#define G1 16                // reduce stage-1 groups (NCHUNK/G1 = 16 chunks each)

typedef float vf4 __attribute__((ext_vector_type(4)));   // clang-native: OK for nontemporal builtin
typedef float vf2 __attribute__((ext_vector_type(2)));

// ---------------- fused: basis (per chunk) + partial dot ----------------
__global__ __launch_bounds__(TI) void kan_partial_kernel(
    const float* __restrict__ coeffs,    // [IN][OUT][N_BASIS]
    const float* __restrict__ bw,        // [IN][OUT]
    const float* __restrict__ x,         // [IN]
    float* __restrict__ partials) {      // [NCHUNK][OUT]
    __shared__ float4 w4[JCHUNK][2];     // {B0..B3},{B4,B5,silu,pad} per j
    const int tid = threadIdx.x;
    const int j0 = blockIdx.y * JCHUNK;

    if (tid < JCHUNK) {
        float xv = x[j0 + tid];
        float t[NUM_KNOTS];
#pragma unroll
        for (int m = 0; m < NUM_KNOTS; ++m)
            t[m] = -1.0f + (2.0f / 9.0f) * (float)m;
        float N[NUM_KNOTS - 1];
#pragma unroll
        for (int m = 0; m < NUM_KNOTS - 1; ++m)
            N[m] = (xv >= t[m] && xv < t[m + 1]) ? 1.0f : 0.0f;
#pragma unroll
        for (int d = 1; d <= DEGREE; ++d) {
#pragma unroll
            for (int m = 0; m + d < NUM_KNOTS - 1; ++m) {
                float ld = t[m + d] - t[m];
                float rd = t[m + d + 1] - t[m + 1];
                float lv = (ld > 0.0f) ? (xv - t[m]) / ld * N[m] : 0.0f;
                float rv = (rd > 0.0f) ? (t[m + d + 1] - xv) / rd * N[m + 1] : 0.0f;
                N[m] = lv + rv;
            }
        }
        float* wp = (float*)&w4[tid][0];
#pragma unroll
        for (int k = 0; k < N_BASIS; ++k) wp[k] = N[k];
        wp[6] = xv / (1.0f + expf(-xv));   // silu
        wp[7] = 0.0f;
    }
    __syncthreads();

    const int i0 = blockIdx.x * IBLK + tid * OPT;     // first of this thread's 2 outputs
    const vf4* cp = (const vf4*)(coeffs + ((size_t)j0 * OUT_FEAT + i0) * N_BASIS);
    const vf2* bp = (const vf2*)(bw + (size_t)j0 * OUT_FEAT + i0);

    float acc0 = 0.0f, acc1 = 0.0f;
#pragma unroll 4
    for (int j = 0; j < JCHUNK; ++j) {
        vf4 a = __builtin_nontemporal_load(cp + 0);  // i0:   c0 c1 c2 c3
        vf4 b = __builtin_nontemporal_load(cp + 1);  //       c4 c5 | i0+1: c0 c1
        vf4 c = __builtin_nontemporal_load(cp + 2);  //       c2 c3 c4 c5
        vf2 bb = __builtin_nontemporal_load(bp);
        float4 w0 = w4[j][0];             // B0..B3   (LDS broadcast)
        float4 w1 = w4[j][1];             // B4,B5,silu,pad
        acc0 += a.x * w0.x + a.y * w0.y + a.z * w0.z + a.w * w0.w
              + b.x * w1.x + b.y * w1.y + bb.x * w1.z;
        acc1 += b.z * w0.x + b.w * w0.y + c.x * w0.z + c.y * w0.w
              + c.z * w1.x + c.w * w1.y + bb.y * w1.z;
        cp += OUT_FEAT * N_BASIS / 4;
        bp += OUT_FEAT / 2;
    }
    float2* pp = (float2*)(partials + (size_t)blockIdx.y * OUT_FEAT + i0);
    pp[0] = make_float2(acc0, acc1);
}

// ---------------- deterministic two-stage reduce ----------------
__global__ __launch_bounds__(256) void kan_reduce1_kernel(
    const float* __restrict__ partials,  // [NCHUNK][OUT]
    float* __restrict__ tmp) {           // [G1][OUT]
    int i = blockIdx.x * 256 + threadIdx.x;
    int g = blockIdx.y;
    float acc = 0.0f;
#pragma unroll
    for (int c = 0; c < NCHUNK / G1; ++c)
        acc += partials[(size_t)(g * (NCHUNK / G1) + c) * OUT_FEAT + i];
    tmp[(size_t)g * OUT_FEAT + i] = acc;
}

__global__ __launch_bounds__(256) void kan_reduce2_kernel(
    const float* __restrict__ tmp,       // [G1][OUT]
    float* __restrict__ out) {           // [OUT]
    int i = blockIdx.x * 256 + threadIdx.x;
    float acc = 0.0f;
#pragma unroll
    for (int g = 0; g < G1; ++g)
        acc += tmp[(size_t)g * OUT_FEAT + i];
    out[i] = acc;
}

extern "C" void kernel_launch(void* const* d_in, const int* in_sizes, int n_in,
                              void* d_out, int out_size, void* d_ws, size_t ws_size,
                              hipStream_t stream) {
    const float* x      = (const float*)d_in[0];   // [4096]
    const float* coeffs = (const float*)d_in[1];   // [4096][2048][6]
    const float* bw     = (const float*)d_in[2];   // [4096][2048]
    float* out = (float*)d_out;                    // [2048] fp32

    float* partials = (float*)d_ws;                          // NCHUNK*2048 floats (2 MB)
    float* tmp      = partials + (size_t)NCHUNK * OUT_FEAT;  // G1*2048 floats (128 KB)

    dim3 grid(OUT_FEAT / IBLK, NCHUNK);            // (4, 256) = 1024 blocks
    kan_partial_kernel<<<grid, TI, 0, stream>>>(coeffs, bw, x, partials);

    dim3 rgrid(OUT_FEAT / 256, G1);                // (8, 16) = 128 blocks
    kan_reduce1_kernel<<<rgrid, 256, 0, stream>>>(partials, tmp);

    kan_reduce2_kernel<<<OUT_FEAT / 256, 256, 0, stream>>>(tmp, out);
}

// Round 9
// 43.103 us; speedup vs baseline: 4.2054x; 1.3787x over previous
//
#include <hip/hip_runtime.h>
#include <math.h>

#define IN_FEAT 4096
#define OUT_FEAT 2048
#define NUM_KNOTS 10
#define DEGREE 3
#define N_BASIS 6            // NUM_KNOTS - DEGREE - 1

#define TI 256               // threads per block (main kernel)
#define OPT 2                // outputs per thread
#define IBLK (TI * OPT)      // 512 outputs per block
#define JCHUNK 16            // input rows per chunk
#define NCHUNK (IN_FEAT / JCHUNK)   // 256
#define G1 16                // reduce stage-1 groups (NCHUNK/G1 = 16 chunks each)

// ---------------- fused: basis (per chunk) + partial dot ----------------
// Best-known config (round 2): 1024 blocks, 4/CU, ~6.3 TB/s delivered =
// measured read-stream ceiling (m13: 6.29 TB/s). nt-loads regress (L3 assist
// lost); JCHUNK=8 regresses (fixed costs); fused reduction regresses.
__global__ __launch_bounds__(TI) void kan_partial_kernel(
    const float* __restrict__ coeffs,    // [IN][OUT][N_BASIS]
    const float* __restrict__ bw,        // [IN][OUT]
    const float* __restrict__ x,         // [IN]
    float* __restrict__ partials) {      // [NCHUNK][OUT]
    __shared__ float4 w4[JCHUNK][2];     // {B0..B3},{B4,B5,silu,pad} per j
    const int tid = threadIdx.x;
    const int j0 = blockIdx.y * JCHUNK;

    if (tid < JCHUNK) {
        float xv = x[j0 + tid];
        float t[NUM_KNOTS];
#pragma unroll
        for (int m = 0; m < NUM_KNOTS; ++m)
            t[m] = -1.0f + (2.0f / 9.0f) * (float)m;
        float N[NUM_KNOTS - 1];
#pragma unroll
        for (int m = 0; m < NUM_KNOTS - 1; ++m)
            N[m] = (xv >= t[m] && xv < t[m + 1]) ? 1.0f : 0.0f;
#pragma unroll
        for (int d = 1; d <= DEGREE; ++d) {
#pragma unroll
            for (int m = 0; m + d < NUM_KNOTS - 1; ++m) {
                float ld = t[m + d] - t[m];
                float rd = t[m + d + 1] - t[m + 1];
                float lv = (ld > 0.0f) ? (xv - t[m]) / ld * N[m] : 0.0f;
                float rv = (rd > 0.0f) ? (t[m + d + 1] - xv) / rd * N[m + 1] : 0.0f;
                N[m] = lv + rv;
            }
        }
        float* wp = (float*)&w4[tid][0];
#pragma unroll
        for (int k = 0; k < N_BASIS; ++k) wp[k] = N[k];
        wp[6] = xv / (1.0f + expf(-xv));   // silu
        wp[7] = 0.0f;
    }
    __syncthreads();

    const int i0 = blockIdx.x * IBLK + tid * OPT;     // first of this thread's 2 outputs
    const float4* cp = (const float4*)(coeffs + ((size_t)j0 * OUT_FEAT + i0) * N_BASIS);
    const float2* bp = (const float2*)(bw + (size_t)j0 * OUT_FEAT + i0);

    float acc0 = 0.0f, acc1 = 0.0f;
#pragma unroll 4
    for (int j = 0; j < JCHUNK; ++j) {
        float4 a = cp[0];                 // i0:   c0 c1 c2 c3
        float4 b = cp[1];                 //       c4 c5 | i0+1: c0 c1
        float4 c = cp[2];                 //       c2 c3 c4 c5
        float2 bb = bp[0];
        float4 w0 = w4[j][0];             // B0..B3   (LDS broadcast)
        float4 w1 = w4[j][1];             // B4,B5,silu,pad
        acc0 += a.x * w0.x + a.y * w0.y + a.z * w0.z + a.w * w0.w
              + b.x * w1.x + b.y * w1.y + bb.x * w1.z;
        acc1 += b.z * w0.x + b.w * w0.y + c.x * w0.z + c.y * w0.w
              + c.z * w1.x + c.w * w1.y + bb.y * w1.z;
        cp += OUT_FEAT * N_BASIS / 4;
        bp += OUT_FEAT / 2;
    }
    float2* pp = (float2*)(partials + (size_t)blockIdx.y * OUT_FEAT + i0);
    pp[0] = make_float2(acc0, acc1);
}

// ---------------- deterministic two-stage reduce ----------------
__global__ __launch_bounds__(256) void kan_reduce1_kernel(
    const float* __restrict__ partials,  // [NCHUNK][OUT]
    float* __restrict__ tmp) {           // [G1][OUT]
    int i = blockIdx.x * 256 + threadIdx.x;
    int g = blockIdx.y;
    float acc = 0.0f;
#pragma unroll
    for (int c = 0; c < NCHUNK / G1; ++c)
        acc += partials[(size_t)(g * (NCHUNK / G1) + c) * OUT_FEAT + i];
    tmp[(size_t)g * OUT_FEAT + i] = acc;
}

__global__ __launch_bounds__(256) void kan_reduce2_kernel(
    const float* __restrict__ tmp,       // [G1][OUT]
    float* __restrict__ out) {           // [OUT]
    int i = blockIdx.x * 256 + threadIdx.x;
    float acc = 0.0f;
#pragma unroll
    for (int g = 0; g < G1; ++g)
        acc += tmp[(size_t)g * OUT_FEAT + i];
    out[i] = acc;
}

extern "C" void kernel_launch(void* const* d_in, const int* in_sizes, int n_in,
                              void* d_out, int out_size, void* d_ws, size_t ws_size,
                              hipStream_t stream) {
    const float* x      = (const float*)d_in[0];   // [4096]
    const float* coeffs = (const float*)d_in[1];   // [4096][2048][6]
    const float* bw     = (const float*)d_in[2];   // [4096][2048]
    float* out = (float*)d_out;                    // [2048] fp32

    float* partials = (float*)d_ws;                          // NCHUNK*2048 floats (2 MB)
    float* tmp      = partials + (size_t)NCHUNK * OUT_FEAT;  // G1*2048 floats (128 KB)

    dim3 grid(OUT_FEAT / IBLK, NCHUNK);            // (4, 256) = 1024 blocks
    kan_partial_kernel<<<grid, TI, 0, stream>>>(coeffs, bw, x, partials);

    dim3 rgrid(OUT_FEAT / 256, G1);                // (8, 16) = 128 blocks
    kan_reduce1_kernel<<<rgrid, 256, 0, stream>>>(partials, tmp);

    kan_reduce2_kernel<<<OUT_FEAT / 256, 256, 0, stream>>>(tmp, out);
}